// Round 6
// baseline (822.844 us; speedup 1.0000x reference)
//
#include <hip/hip_runtime.h>
#include <utility>

#define HH 20

typedef float v2f __attribute__((ext_vector_type(2)));

// Raw v_rcp_f32 (~1 ulp); harness threshold 1.9e-3.
__device__ __forceinline__ float fast_rcp(float x) { return __builtin_amdgcn_rcpf(x); }
__device__ __forceinline__ float fsigmoid(float x) { return fast_rcp(1.0f + __expf(-x)); }
__device__ __forceinline__ float ftanh(float x) {
    float e = __expf(2.0f * x);
    return 1.0f - 2.0f * fast_rcp(e + 1.0f);
}
// DPP quad_perm XOR patterns within each aligned 4-lane quad (VALU pipe).
constexpr int XOR1 = 0xB1;  // [1,0,3,2]
constexpr int XOR2 = 0x4E;  // [2,3,0,1]
constexpr int XOR3 = 0x1B;  // [3,2,1,0]
template <int CTRL>
__device__ __forceinline__ float qdpp(float v) {
    return __int_as_float(__builtin_amdgcn_mov_dpp(__float_as_int(v), CTRL, 0xF, 0xF, true));
}
// v_pk_fma_f32: two independent IEEE fp32 FMAs per instruction.
__device__ __forceinline__ v2f fma2(v2f a, v2f b, v2f c) {
#if __has_builtin(__builtin_elementwise_fma)
    return __builtin_elementwise_fma(a, b, c);
#else
    v2f r; r.x = fmaf(a.x, b.x, c.x); r.y = fmaf(a.y, b.y, c.y); return r;
#endif
}
__device__ __forceinline__ v2f splat2(float w) { return v2f{w, w}; }

// ---- LDS weight arena with per-gate bank pads (R0-verified layout) ----------
// Gate block g at offset g*(20*IN+4): the wave's four concurrent gate-row
// addresses land on disjoint bank quads (checked mod-32-bank arithmetic for
// BLK16/BLK20/BLK4).
constexpr int BLK16 = 20 * 16 + 4;   // 324
constexpr int BLK20 = 20 * 20 + 4;   // 404
constexpr int BLK4  = 20 * 4 + 4;    // 84

constexpr int W_Wih1_0 = 0;
constexpr int W_Whh1_0 = W_Wih1_0 + 4 * BLK16;    // 1296
constexpr int W_b1_0   = W_Whh1_0 + 4 * BLK20;    // 2912
constexpr int W_Wih1_1 = W_b1_0 + 80;             // 2992
constexpr int W_Whh1_1 = W_Wih1_1 + 4 * BLK20;    // 4608
constexpr int W_b1_1   = W_Whh1_1 + 4 * BLK20;    // 6224
constexpr int W_Wih2_0 = W_b1_1 + 80;             // 6304
constexpr int W_Whh2_0 = W_Wih2_0 + 4 * BLK4;     // 6640
constexpr int W_b2_0   = W_Whh2_0 + 4 * BLK20;    // 8256
constexpr int W_Wih2_1 = W_b2_0 + 80;             // 8336
constexpr int W_Whh2_1 = W_Wih2_1 + 4 * BLK20;    // 9952
constexpr int W_b2_1   = W_Whh2_1 + 4 * BLK20;    // 11568
constexpr int W_fW1    = W_b2_1 + 80;             // 11648
constexpr int W_fb1    = W_fW1 + 200;             // 11848
constexpr int W_fW2    = W_fb1 + 12;              // 11860
constexpr int W_fb2    = W_fW2 + 100;             // 11960
constexpr int W_fW3    = W_fb2 + 12;              // 11972
constexpr int W_fb3    = W_fW3 + 10;              // 11982
constexpr int LDS_TOT  = W_fb3 + 2;               // 11984 floats = 47.9 KB

// One float4 weight chunk (lane's own gate row) feeds 4 quad elements:
// 8 pk-fma = 16 scalar FMAs per 16B LDS read.
template <int IN, size_t U, size_t K>
__device__ __forceinline__ void rowq_k(const float (&sm)[LDS_TOT], int rb,
                                       const v2f (&p01)[IN], const v2f (&p23)[IN],
                                       v2f& a01, v2f& a23) {
    float4 w = *(const float4*)&sm[rb + (int)(U * IN + 4 * K)];
    v2f w0 = splat2(w.x), w1 = splat2(w.y), w2 = splat2(w.z), w3 = splat2(w.w);
    a01 = fma2(w0, p01[4 * K + 0], a01);  a23 = fma2(w0, p23[4 * K + 0], a23);
    a01 = fma2(w1, p01[4 * K + 1], a01);  a23 = fma2(w1, p23[4 * K + 1], a23);
    a01 = fma2(w2, p01[4 * K + 2], a01);  a23 = fma2(w2, p23[4 * K + 2], a23);
    a01 = fma2(w3, p01[4 * K + 3], a01);  a23 = fma2(w3, p23[4 * K + 3], a23);
}
template <int IN, size_t U, size_t... K>
__device__ __forceinline__ void rowq(const float (&sm)[LDS_TOT], int rb,
                                     const v2f (&p01)[IN], const v2f (&p23)[IN],
                                     v2f& a01, v2f& a23, std::index_sequence<K...>) {
    (rowq_k<IN, U, K>(sm, rb, p01, p23, a01, a23), ...);
}

// One LSTM unit, quad-split: lane q computes gate q (i=0,f=1,g=2,o=3) for the
// quad's 4 elements in LOCAL order (own, q^1, q^2, q^3). Operand quads are in
// local order too, so the weight splat is order-agnostic. The gather-back of
// own-element gates uses fixed components (local order makes them
// lane-independent): c_k = qdpp<XORk>(act at local slot k).
// h[U] is updated IN PLACE: all units read only the hp quad copies, so the
// old h value is dead once the quads are built (saves the hn copy-back regs).
template <int IN, size_t U>
__device__ __forceinline__ void unitq(const float (&sm)[LDS_TOT], bool q0, bool q1,
                                      float m, float mm1, int rih, int rhh, int rb,
                                      const v2f (&xp01)[IN], const v2f (&xp23)[IN],
                                      const v2f (&hp01)[HH], const v2f (&hp23)[HH],
                                      float (&c)[HH], float (&h)[HH]) {
    float bv = sm[rb + (int)U];
    v2f a01 = splat2(bv), a23 = splat2(bv);
    rowq<IN, U>(sm, rih, xp01, xp23, a01, a23, std::make_index_sequence<IN / 4>{});
    rowq<HH, U>(sm, rhh, hp01, hp23, a01, a23, std::make_index_sequence<HH / 4>{});
    // m-trick activation (R0-verified): m=1 -> sigma, m=2 -> tanh
    float act0 = fmaf(m, fsigmoid(m * a01.x), -mm1);
    float act1 = fmaf(m, fsigmoid(m * a01.y), -mm1);
    float act2 = fmaf(m, fsigmoid(m * a23.x), -mm1);
    float act3 = fmaf(m, fsigmoid(m * a23.y), -mm1);
    // gather own element's four gates: c_k = gate (q^k) of own element
    float c0 = act0;
    float c1 = qdpp<XOR1>(act1);
    float c2 = qdpp<XOR2>(act2);
    float c3 = qdpp<XOR3>(act3);
    // role un-permute (XOR by q, 2 stages of 4 cndmask) -- verified for q=0..3
    float u0 = q0 ? c1 : c0, u1 = q0 ? c0 : c1, u2 = q0 ? c3 : c2, u3 = q0 ? c2 : c3;
    float si = q1 ? u2 : u0, sf = q1 ? u3 : u1, tg = q1 ? u0 : u2, so = q1 ? u1 : u3;
    float cn = fmaf(sf, c[U], si * tg);
    c[U] = cn;
    h[U] = so * ftanh(cn);
}

// RESTORE: for layer-2 cells the "x" input is the layer-1 h, which is needed
// again next timestep. Instead of keeping it live through the gemm (20 VGPRs
// at the pressure peak), recover it afterwards from the quad copy
// (xp01[K].x == own x[K]); its old registers die at quad-build time.
template <int WIH, int WHH, int BOFF, int IN, int BLK, bool RESTORE,
          size_t... U, size_t... K>
__device__ __forceinline__ void cell_impl(const float (&sm)[LDS_TOT], int wb, int q,
                                          bool q0, bool q1, float m, float mm1,
                                          float (&x)[IN],
                                          float (&h)[HH], float (&c)[HH],
                                          std::index_sequence<U...>, std::index_sequence<K...>) {
    // quad operand vectors in local order: (own, q^1 | q^2, q^3); 3 DPP/scalar
    v2f xp01[IN], xp23[IN], hp01[HH], hp23[HH];
    ((xp01[K] = v2f{x[K], qdpp<XOR1>(x[K])},
      xp23[K] = v2f{qdpp<XOR2>(x[K]), qdpp<XOR3>(x[K])}), ...);
    ((hp01[U] = v2f{h[U], qdpp<XOR1>(h[U])},
      hp23[U] = v2f{qdpp<XOR2>(h[U]), qdpp<XOR3>(h[U])}), ...);
    const int rih = wb + WIH + q * BLK;    // own gate's row blocks (per-lane addr)
    const int rhh = wb + WHH + q * BLK20;
    const int rb  = wb + BOFF + q * 20;
    (unitq<IN, U>(sm, q0, q1, m, mm1, rih, rhh, rb,
                  xp01, xp23, hp01, hp23, c, h), ...);
    if constexpr (RESTORE) { ((x[K] = xp01[K].x), ...); }
}

template <int WIH, int WHH, int BOFF, int IN, int BLK, bool RESTORE = false>
__device__ __forceinline__ void cell(const float (&sm)[LDS_TOT], int wb, int q,
                                     bool q0, bool q1, float m, float mm1,
                                     float (&x)[IN],
                                     float (&h)[HH], float (&c)[HH]) {
    cell_impl<WIH, WHH, BOFF, IN, BLK, RESTORE>(sm, wb, q, q0, q1, m, mm1, x, h, c,
                                                std::make_index_sequence<HH>{},
                                                std::make_index_sequence<IN>{});
}

// ---- MLP: serial structure (own element, uniform LDS reads) -----------------
template <int WOFF, size_t J, int LD, int NV, size_t... K>
__device__ __forceinline__ float mlp_dot(const float (&sm)[LDS_TOT], int wb, const float (&v)[NV],
                                         float a, std::index_sequence<K...>) {
    ((a = fmaf(sm[wb + WOFF + (int)(J * LD + K)], v[K], a)), ...);
    return a;
}
template <size_t... J>
__device__ __forceinline__ void mlp_l1(const float (&sm)[LDS_TOT], int wb,
                                       const float (&h)[HH], float (&z)[10], std::index_sequence<J...>) {
    ((z[J] = fmaxf(mlp_dot<W_fW1, J, HH>(sm, wb, h, sm[wb + W_fb1 + (int)J],
                                         std::make_index_sequence<HH>{}), 0.f)), ...);
}
template <size_t... J>
__device__ __forceinline__ void mlp_l2(const float (&sm)[LDS_TOT], int wb,
                                       const float (&z1)[10], float (&z2)[10], std::index_sequence<J...>) {
    ((z2[J] = fmaxf(mlp_dot<W_fW2, J, 10>(sm, wb, z1, sm[wb + W_fb2 + (int)J],
                                          std::make_index_sequence<10>{}), 0.f)), ...);
}

// __launch_bounds__(256, 1): min-waves-per-EU = 1 unlocks the full VGPR budget.
// Empirical mapping on this toolchain: min-waves 2 -> 128-VGPR cap (R4/R5,
// 348 MB spill traffic); min-waves 1 -> >=212 proven by R3. Runtime occupancy
// is set by the ACTUAL count: <=256 VGPR still runs 2 waves/SIMD (grid/LDS cap).
__global__ void __launch_bounds__(256, 1) lstm_ar_kernel(
    const float* __restrict__ y_past, const float* __restrict__ x_past,
    const float* __restrict__ u_past, const float* __restrict__ s_past,
    const float* __restrict__ u_future,
    const float* __restrict__ Wih1_0, const float* __restrict__ Whh1_0, const float* __restrict__ b1_0,
    const float* __restrict__ Wih1_1, const float* __restrict__ Whh1_1, const float* __restrict__ b1_1,
    const float* __restrict__ Wih2_0, const float* __restrict__ Whh2_0, const float* __restrict__ b2_0,
    const float* __restrict__ Wih2_1, const float* __restrict__ Whh2_1, const float* __restrict__ b2_1,
    const float* __restrict__ fW1, const float* __restrict__ fb1,
    const float* __restrict__ fW2, const float* __restrict__ fb2,
    const float* __restrict__ fW3, const float* __restrict__ fb3,
    float* __restrict__ out, int B) {
    __shared__ __align__(16) float smem[LDS_TOT];
    const int tid = threadIdx.x;

    // ---- stage weights into LDS with per-gate +4 pads (R0-identical) ----
    auto stage_w = [&](const float* src, int off, int IN) {
        const int gb = 20 * IN;
        for (int i = tid; i < 4 * gb; i += 256) {
            int g = i / gb;
            smem[off + g * (gb + 4) + (i - g * gb)] = src[i];
        }
    };
    auto stage = [&](const float* src, int off, int n) {
        for (int i = tid; i < n; i += 256) smem[off + i] = src[i];
    };
    stage_w(Wih1_0, W_Wih1_0, 16);
    stage_w(Whh1_0, W_Whh1_0, 20);
    stage(b1_0, W_b1_0, 80);
    stage_w(Wih1_1, W_Wih1_1, 20);
    stage_w(Whh1_1, W_Whh1_1, 20);
    stage(b1_1, W_b1_1, 80);
    stage_w(Wih2_0, W_Wih2_0, 4);
    stage_w(Whh2_0, W_Whh2_0, 20);
    stage(b2_0, W_b2_0, 80);
    stage_w(Wih2_1, W_Wih2_1, 20);
    stage_w(Whh2_1, W_Whh2_1, 20);
    stage(b2_1, W_b2_1, 80);
    stage(fW1, W_fW1, 200);
    stage(fb1, W_fb1, 10);
    stage(fW2, W_fW2, 100);
    stage(fb2, W_fb2, 10);
    stage(fW3, W_fW3, 10);
    stage(fb3, W_fb3, 1);
    __syncthreads();

    const int q = tid & 3;                    // quad lane: gate i/f/g/o
    const bool q0 = (tid & 1) != 0;
    const bool q1 = (tid & 2) != 0;
    const int e = blockIdx.x * 256 + tid;     // OWN element == global thread id
    if (e >= B) return;                       // never taken (B % 256 == 0)

    const float m   = (q == 2) ? 2.0f : 1.0f; // tanh for the cell gate
    const float mm1 = m - 1.0f;

    // own-element state only: 80 registers
    float h0[HH], c0[HH], h1[HH], c1[HH];
    {
        auto zero = [&](auto... u) {
            ((h0[u] = 0.f, c0[u] = 0.f, h1[u] = 0.f, c1[u] = 0.f), ...);
        };
        zero(0, 1, 2, 3, 4, 5, 6, 7, 8, 9, 10, 11, 12, 13, 14, 15, 16, 17, 18, 19);
    }

    int wb = 0;  // laundered weight base: re-opaqued per timestep (kills LICM hoist)

    // ---- encoder over lookback T=8 (input = concat[y,x,u,s] = 16 feats) ----
#pragma clang loop unroll(disable)
    for (int t = 0; t < 8; ++t) {
        asm volatile("" : "+s"(wb));
        float x[16];
        x[0] = y_past[e * 8 + t];
        {
            const float4* p = (const float4*)(x_past + (size_t)(e * 8 + t) * 8);
            float4 a0 = p[0], a1 = p[1];
            x[1] = a0.x; x[2] = a0.y; x[3] = a0.z; x[4] = a0.w;
            x[5] = a1.x; x[6] = a1.y; x[7] = a1.z; x[8] = a1.w;
        }
        {
            const float4* p = (const float4*)(u_past + (size_t)(e * 8 + t) * 4);
            float4 a0 = p[0];
            x[9] = a0.x; x[10] = a0.y; x[11] = a0.z; x[12] = a0.w;
        }
        {
            const float* p = s_past + (size_t)(e * 8 + t) * 3;
            x[13] = p[0]; x[14] = p[1]; x[15] = p[2];
        }
        cell<W_Wih1_0, W_Whh1_0, W_b1_0, 16, BLK16>(smem, wb, q, q0, q1, m, mm1, x, h0, c0);
        cell<W_Wih1_1, W_Whh1_1, W_b1_1, HH, BLK20, true>(smem, wb, q, q0, q1, m, mm1, h0, h1, c1);
    }

    // ---- decoder over lookahead T=4 (input = u_future, 4 feats) + MLP head ----
#pragma clang loop unroll(disable)
    for (int t = 0; t < 4; ++t) {
        asm volatile("" : "+s"(wb));
        float x[4];
        {
            const float4* p = (const float4*)(u_future + (size_t)(e * 4 + t) * 4);
            float4 a0 = p[0];
            x[0] = a0.x; x[1] = a0.y; x[2] = a0.z; x[3] = a0.w;
        }
        cell<W_Wih2_0, W_Whh2_0, W_b2_0, 4, BLK4>(smem, wb, q, q0, q1, m, mm1, x, h0, c0);
        cell<W_Wih2_1, W_Whh2_1, W_b2_1, HH, BLK20, true>(smem, wb, q, q0, q1, m, mm1, h0, h1, c1);

        // FCNN 20 -> 10 -> 10 -> 1 on OWN element's h1
        float z1[10], z2[10];
        mlp_l1(smem, wb, h1, z1, std::make_index_sequence<10>{});
        mlp_l2(smem, wb, z1, z2, std::make_index_sequence<10>{});
        float o = mlp_dot<W_fW3, 0, 10>(smem, wb, z2, smem[wb + W_fb3],
                                        std::make_index_sequence<10>{});
        out[e * 4 + t] = o;
    }
}

extern "C" void kernel_launch(void* const* d_in, const int* in_sizes, int n_in,
                              void* d_out, int out_size, void* d_ws, size_t ws_size,
                              hipStream_t stream) {
    (void)n_in; (void)d_ws; (void)ws_size;
    const float* y_past   = (const float*)d_in[0];
    const float* x_past   = (const float*)d_in[1];
    const float* u_past   = (const float*)d_in[2];
    const float* s_past   = (const float*)d_in[3];
    const float* u_future = (const float*)d_in[4];
    const float* Wih1_0 = (const float*)d_in[5];
    const float* Whh1_0 = (const float*)d_in[6];
    const float* b1_0   = (const float*)d_in[7];
    const float* Wih1_1 = (const float*)d_in[8];
    const float* Whh1_1 = (const float*)d_in[9];
    const float* b1_1   = (const float*)d_in[10];
    const float* Wih2_0 = (const float*)d_in[11];
    const float* Whh2_0 = (const float*)d_in[12];
    const float* b2_0   = (const float*)d_in[13];
    const float* Wih2_1 = (const float*)d_in[14];
    const float* Whh2_1 = (const float*)d_in[15];
    const float* b2_1   = (const float*)d_in[16];
    const float* fW1 = (const float*)d_in[17];
    const float* fb1 = (const float*)d_in[18];
    const float* fW2 = (const float*)d_in[19];
    const float* fb2 = (const float*)d_in[20];
    const float* fW3 = (const float*)d_in[21];
    const float* fb3 = (const float*)d_in[22];
    float* out = (float*)d_out;

    int B = in_sizes[0] / 8;  // y_past is [B,8,1]
    (void)out_size;

    dim3 block(256);
    dim3 grid((B + 255) / 256);
    lstm_ar_kernel<<<grid, block, 0, stream>>>(
        y_past, x_past, u_past, s_past, u_future,
        Wih1_0, Whh1_0, b1_0, Wih1_1, Whh1_1, b1_1,
        Wih2_0, Whh2_0, b2_0, Wih2_1, Whh2_1, b2_1,
        fW1, fb1, fW2, fb2, fW3, fb3, out, B);
}

// Round 8
// 597.501 us; speedup vs baseline: 1.3771x; 1.3771x over previous
//
#include <hip/hip_runtime.h>
#include <utility>

#define HH 20

typedef float v2f __attribute__((ext_vector_type(2)));

// Raw v_rcp_f32 (~1 ulp); harness threshold 1.9e-3.
__device__ __forceinline__ float fast_rcp(float x) { return __builtin_amdgcn_rcpf(x); }
__device__ __forceinline__ float fsigmoid(float x) { return fast_rcp(1.0f + __expf(-x)); }
__device__ __forceinline__ float ftanh(float x) {
    float e = __expf(2.0f * x);
    return 1.0f - 2.0f * fast_rcp(e + 1.0f);
}
// DPP quad_perm XOR patterns within each aligned 4-lane quad (VALU pipe).
constexpr int XOR1 = 0xB1;  // [1,0,3,2]
constexpr int XOR2 = 0x4E;  // [2,3,0,1]
constexpr int XOR3 = 0x1B;  // [3,2,1,0]
template <int CTRL>
__device__ __forceinline__ float qdpp(float v) {
    return __int_as_float(__builtin_amdgcn_mov_dpp(__float_as_int(v), CTRL, 0xF, 0xF, true));
}
// v_pk_fma_f32: two independent IEEE fp32 FMAs per instruction.
__device__ __forceinline__ v2f fma2(v2f a, v2f b, v2f c) {
#if __has_builtin(__builtin_elementwise_fma)
    return __builtin_elementwise_fma(a, b, c);
#else
    v2f r; r.x = fmaf(a.x, b.x, c.x); r.y = fmaf(a.y, b.y, c.y); return r;
#endif
}
__device__ __forceinline__ v2f splat2(float w) { return v2f{w, w}; }

// ---- LDS weight arena with per-gate bank pads (R0-verified layout) ----------
// Gate block g at offset g*(20*IN+4): the wave's four concurrent gate-row
// addresses land on disjoint bank quads (checked mod-32-bank arithmetic for
// BLK16/BLK20/BLK4).
constexpr int BLK16 = 20 * 16 + 4;   // 324
constexpr int BLK20 = 20 * 20 + 4;   // 404
constexpr int BLK4  = 20 * 4 + 4;    // 84

constexpr int W_Wih1_0 = 0;
constexpr int W_Whh1_0 = W_Wih1_0 + 4 * BLK16;    // 1296
constexpr int W_b1_0   = W_Whh1_0 + 4 * BLK20;    // 2912
constexpr int W_Wih1_1 = W_b1_0 + 80;             // 2992
constexpr int W_Whh1_1 = W_Wih1_1 + 4 * BLK20;    // 4608
constexpr int W_b1_1   = W_Whh1_1 + 4 * BLK20;    // 6224
constexpr int W_Wih2_0 = W_b1_1 + 80;             // 6304
constexpr int W_Whh2_0 = W_Wih2_0 + 4 * BLK4;     // 6640
constexpr int W_b2_0   = W_Whh2_0 + 4 * BLK20;    // 8256
constexpr int W_Wih2_1 = W_b2_0 + 80;             // 8336
constexpr int W_Whh2_1 = W_Wih2_1 + 4 * BLK20;    // 9952
constexpr int W_b2_1   = W_Whh2_1 + 4 * BLK20;    // 11568
constexpr int W_fW1    = W_b2_1 + 80;             // 11648
constexpr int W_fb1    = W_fW1 + 200;             // 11848
constexpr int W_fW2    = W_fb1 + 12;              // 11860
constexpr int W_fb2    = W_fW2 + 100;             // 11960
constexpr int W_fW3    = W_fb2 + 12;              // 11972
constexpr int W_fb3    = W_fW3 + 10;              // 11982
constexpr int LDS_TOT  = W_fb3 + 2;               // 11984 floats = 47.9 KB

// One float4 weight chunk (lane's own gate row) feeds 4 quad elements:
// 8 pk-fma = 16 scalar FMAs per 16B LDS read.
template <int IN, size_t U, size_t K>
__device__ __forceinline__ void rowq_k(const float (&sm)[LDS_TOT], int rb,
                                       const v2f (&p01)[IN], const v2f (&p23)[IN],
                                       v2f& a01, v2f& a23) {
    float4 w = *(const float4*)&sm[rb + (int)(U * IN + 4 * K)];
    v2f w0 = splat2(w.x), w1 = splat2(w.y), w2 = splat2(w.z), w3 = splat2(w.w);
    a01 = fma2(w0, p01[4 * K + 0], a01);  a23 = fma2(w0, p23[4 * K + 0], a23);
    a01 = fma2(w1, p01[4 * K + 1], a01);  a23 = fma2(w1, p23[4 * K + 1], a23);
    a01 = fma2(w2, p01[4 * K + 2], a01);  a23 = fma2(w2, p23[4 * K + 2], a23);
    a01 = fma2(w3, p01[4 * K + 3], a01);  a23 = fma2(w3, p23[4 * K + 3], a23);
}
template <int IN, size_t U, size_t... K>
__device__ __forceinline__ void rowq(const float (&sm)[LDS_TOT], int rb,
                                     const v2f (&p01)[IN], const v2f (&p23)[IN],
                                     v2f& a01, v2f& a23, std::index_sequence<K...>) {
    (rowq_k<IN, U, K>(sm, rb, p01, p23, a01, a23), ...);
}

// One LSTM unit, quad-split: lane q computes gate q (i=0,f=1,g=2,o=3) for the
// quad's 4 elements in LOCAL order (own, q^1, q^2, q^3). Operand quads are in
// local order too, so the weight splat is order-agnostic. The gather-back of
// own-element gates uses fixed components (local order makes them
// lane-independent): c_k = qdpp<XORk>(act at local slot k).
// h[U] is updated IN PLACE: all units read only the hp quad copies, so the
// old h value is dead once the quads are built (saves the hn copy-back regs).
template <int IN, size_t U>
__device__ __forceinline__ void unitq(const float (&sm)[LDS_TOT], bool q0, bool q1,
                                      float m, float mm1, int rih, int rhh, int rb,
                                      const v2f (&xp01)[IN], const v2f (&xp23)[IN],
                                      const v2f (&hp01)[HH], const v2f (&hp23)[HH],
                                      float (&c)[HH], float (&h)[HH]) {
    float bv = sm[rb + (int)U];
    v2f a01 = splat2(bv), a23 = splat2(bv);
    rowq<IN, U>(sm, rih, xp01, xp23, a01, a23, std::make_index_sequence<IN / 4>{});
    rowq<HH, U>(sm, rhh, hp01, hp23, a01, a23, std::make_index_sequence<HH / 4>{});
    // m-trick activation (R0-verified): m=1 -> sigma, m=2 -> tanh
    float act0 = fmaf(m, fsigmoid(m * a01.x), -mm1);
    float act1 = fmaf(m, fsigmoid(m * a01.y), -mm1);
    float act2 = fmaf(m, fsigmoid(m * a23.x), -mm1);
    float act3 = fmaf(m, fsigmoid(m * a23.y), -mm1);
    // gather own element's four gates: c_k = gate (q^k) of own element
    float c0 = act0;
    float c1 = qdpp<XOR1>(act1);
    float c2 = qdpp<XOR2>(act2);
    float c3 = qdpp<XOR3>(act3);
    // role un-permute (XOR by q, 2 stages of 4 cndmask) -- verified for q=0..3
    float u0 = q0 ? c1 : c0, u1 = q0 ? c0 : c1, u2 = q0 ? c3 : c2, u3 = q0 ? c2 : c3;
    float si = q1 ? u2 : u0, sf = q1 ? u3 : u1, tg = q1 ? u0 : u2, so = q1 ? u1 : u3;
    float cn = fmaf(sf, c[U], si * tg);
    c[U] = cn;
    h[U] = so * ftanh(cn);
}

// RESTORE: for layer-2 cells the "x" input is the layer-1 h, which is needed
// again next timestep. Instead of keeping it live through the gemm (20 VGPRs
// at the pressure peak), recover it afterwards from the quad copy
// (xp01[K].x == own x[K]); its old registers die at quad-build time.
template <int WIH, int WHH, int BOFF, int IN, int BLK, bool RESTORE,
          size_t... U, size_t... K>
__device__ __forceinline__ void cell_impl(const float (&sm)[LDS_TOT], int wb, int q,
                                          bool q0, bool q1, float m, float mm1,
                                          float (&x)[IN],
                                          float (&h)[HH], float (&c)[HH],
                                          std::index_sequence<U...>, std::index_sequence<K...>) {
    // quad operand vectors in local order: (own, q^1 | q^2, q^3); 3 DPP/scalar
    v2f xp01[IN], xp23[IN], hp01[HH], hp23[HH];
    ((xp01[K] = v2f{x[K], qdpp<XOR1>(x[K])},
      xp23[K] = v2f{qdpp<XOR2>(x[K]), qdpp<XOR3>(x[K])}), ...);
    ((hp01[U] = v2f{h[U], qdpp<XOR1>(h[U])},
      hp23[U] = v2f{qdpp<XOR2>(h[U]), qdpp<XOR3>(h[U])}), ...);
    const int rih = wb + WIH + q * BLK;    // own gate's row blocks (per-lane addr)
    const int rhh = wb + WHH + q * BLK20;
    const int rb  = wb + BOFF + q * 20;
    (unitq<IN, U>(sm, q0, q1, m, mm1, rih, rhh, rb,
                  xp01, xp23, hp01, hp23, c, h), ...);
    if constexpr (RESTORE) { ((x[K] = xp01[K].x), ...); }
}

template <int WIH, int WHH, int BOFF, int IN, int BLK, bool RESTORE = false>
__device__ __forceinline__ void cell(const float (&sm)[LDS_TOT], int wb, int q,
                                     bool q0, bool q1, float m, float mm1,
                                     float (&x)[IN],
                                     float (&h)[HH], float (&c)[HH]) {
    cell_impl<WIH, WHH, BOFF, IN, BLK, RESTORE>(sm, wb, q, q0, q1, m, mm1, x, h, c,
                                                std::make_index_sequence<HH>{},
                                                std::make_index_sequence<IN>{});
}

// ---- MLP: serial structure (own element, uniform LDS reads) -----------------
template <int WOFF, size_t J, int LD, int NV, size_t... K>
__device__ __forceinline__ float mlp_dot(const float (&sm)[LDS_TOT], int wb, const float (&v)[NV],
                                         float a, std::index_sequence<K...>) {
    ((a = fmaf(sm[wb + WOFF + (int)(J * LD + K)], v[K], a)), ...);
    return a;
}
template <size_t... J>
__device__ __forceinline__ void mlp_l1(const float (&sm)[LDS_TOT], int wb,
                                       const float (&h)[HH], float (&z)[10], std::index_sequence<J...>) {
    ((z[J] = fmaxf(mlp_dot<W_fW1, J, HH>(sm, wb, h, sm[wb + W_fb1 + (int)J],
                                         std::make_index_sequence<HH>{}), 0.f)), ...);
}
template <size_t... J>
__device__ __forceinline__ void mlp_l2(const float (&sm)[LDS_TOT], int wb,
                                       const float (&z1)[10], float (&z2)[10], std::index_sequence<J...>) {
    ((z2[J] = fmaxf(mlp_dot<W_fW2, J, 10>(sm, wb, z1, sm[wb + W_fb2 + (int)J],
                                          std::make_index_sequence<10>{}), 0.f)), ...);
}

// Knob truth table (measured on this toolchain/HW):
//   min-waves=2  (lb(256,2), wpe(2,2))   -> 128-VGPR compile cap -> 348MB spills
//   min-waves=1  (lb(128,1), lb(256,1))  -> big alloc (160, no spill) BUT
//                                           runtime capped at 1 wave/EU (11.8%)
// wpe(1,2) takes the uncovered middle: min=1 keeps the spill-free 160-VGPR
// allocation; explicit max=2 lifts the runtime residency cap to 2 waves/EU
// (VGPR 160 <= 256 boundary, LDS 2x48KB <= 160KB, grid = 2 blocks/CU).
__global__ void __launch_bounds__(256)
__attribute__((amdgpu_waves_per_eu(1, 2))) lstm_ar_kernel(
    const float* __restrict__ y_past, const float* __restrict__ x_past,
    const float* __restrict__ u_past, const float* __restrict__ s_past,
    const float* __restrict__ u_future,
    const float* __restrict__ Wih1_0, const float* __restrict__ Whh1_0, const float* __restrict__ b1_0,
    const float* __restrict__ Wih1_1, const float* __restrict__ Whh1_1, const float* __restrict__ b1_1,
    const float* __restrict__ Wih2_0, const float* __restrict__ Whh2_0, const float* __restrict__ b2_0,
    const float* __restrict__ Wih2_1, const float* __restrict__ Whh2_1, const float* __restrict__ b2_1,
    const float* __restrict__ fW1, const float* __restrict__ fb1,
    const float* __restrict__ fW2, const float* __restrict__ fb2,
    const float* __restrict__ fW3, const float* __restrict__ fb3,
    float* __restrict__ out, int B) {
    __shared__ __align__(16) float smem[LDS_TOT];
    const int tid = threadIdx.x;

    // ---- stage weights into LDS with per-gate +4 pads (R0-identical) ----
    auto stage_w = [&](const float* src, int off, int IN) {
        const int gb = 20 * IN;
        for (int i = tid; i < 4 * gb; i += 256) {
            int g = i / gb;
            smem[off + g * (gb + 4) + (i - g * gb)] = src[i];
        }
    };
    auto stage = [&](const float* src, int off, int n) {
        for (int i = tid; i < n; i += 256) smem[off + i] = src[i];
    };
    stage_w(Wih1_0, W_Wih1_0, 16);
    stage_w(Whh1_0, W_Whh1_0, 20);
    stage(b1_0, W_b1_0, 80);
    stage_w(Wih1_1, W_Wih1_1, 20);
    stage_w(Whh1_1, W_Whh1_1, 20);
    stage(b1_1, W_b1_1, 80);
    stage_w(Wih2_0, W_Wih2_0, 4);
    stage_w(Whh2_0, W_Whh2_0, 20);
    stage(b2_0, W_b2_0, 80);
    stage_w(Wih2_1, W_Wih2_1, 20);
    stage_w(Whh2_1, W_Whh2_1, 20);
    stage(b2_1, W_b2_1, 80);
    stage(fW1, W_fW1, 200);
    stage(fb1, W_fb1, 10);
    stage(fW2, W_fW2, 100);
    stage(fb2, W_fb2, 10);
    stage(fW3, W_fW3, 10);
    stage(fb3, W_fb3, 1);
    __syncthreads();

    const int q = tid & 3;                    // quad lane: gate i/f/g/o
    const bool q0 = (tid & 1) != 0;
    const bool q1 = (tid & 2) != 0;
    const int e = blockIdx.x * 256 + tid;     // OWN element == global thread id
    if (e >= B) return;                       // never taken (B % 256 == 0)

    const float m   = (q == 2) ? 2.0f : 1.0f; // tanh for the cell gate
    const float mm1 = m - 1.0f;

    // own-element state only: 80 registers
    float h0[HH], c0[HH], h1[HH], c1[HH];
    {
        auto zero = [&](auto... u) {
            ((h0[u] = 0.f, c0[u] = 0.f, h1[u] = 0.f, c1[u] = 0.f), ...);
        };
        zero(0, 1, 2, 3, 4, 5, 6, 7, 8, 9, 10, 11, 12, 13, 14, 15, 16, 17, 18, 19);
    }

    int wb = 0;  // laundered weight base: re-opaqued per timestep (kills LICM hoist)

    // ---- encoder over lookback T=8 (input = concat[y,x,u,s] = 16 feats) ----
#pragma clang loop unroll(disable)
    for (int t = 0; t < 8; ++t) {
        asm volatile("" : "+s"(wb));
        float x[16];
        x[0] = y_past[e * 8 + t];
        {
            const float4* p = (const float4*)(x_past + (size_t)(e * 8 + t) * 8);
            float4 a0 = p[0], a1 = p[1];
            x[1] = a0.x; x[2] = a0.y; x[3] = a0.z; x[4] = a0.w;
            x[5] = a1.x; x[6] = a1.y; x[7] = a1.z; x[8] = a1.w;
        }
        {
            const float4* p = (const float4*)(u_past + (size_t)(e * 8 + t) * 4);
            float4 a0 = p[0];
            x[9] = a0.x; x[10] = a0.y; x[11] = a0.z; x[12] = a0.w;
        }
        {
            const float* p = s_past + (size_t)(e * 8 + t) * 3;
            x[13] = p[0]; x[14] = p[1]; x[15] = p[2];
        }
        cell<W_Wih1_0, W_Whh1_0, W_b1_0, 16, BLK16>(smem, wb, q, q0, q1, m, mm1, x, h0, c0);
        cell<W_Wih1_1, W_Whh1_1, W_b1_1, HH, BLK20, true>(smem, wb, q, q0, q1, m, mm1, h0, h1, c1);
    }

    // ---- decoder over lookahead T=4 (input = u_future, 4 feats) + MLP head ----
#pragma clang loop unroll(disable)
    for (int t = 0; t < 4; ++t) {
        asm volatile("" : "+s"(wb));
        float x[4];
        {
            const float4* p = (const float4*)(u_future + (size_t)(e * 4 + t) * 4);
            float4 a0 = p[0];
            x[0] = a0.x; x[1] = a0.y; x[2] = a0.z; x[3] = a0.w;
        }
        cell<W_Wih2_0, W_Whh2_0, W_b2_0, 4, BLK4>(smem, wb, q, q0, q1, m, mm1, x, h0, c0);
        cell<W_Wih2_1, W_Whh2_1, W_b2_1, HH, BLK20, true>(smem, wb, q, q0, q1, m, mm1, h0, h1, c1);

        // FCNN 20 -> 10 -> 10 -> 1 on OWN element's h1
        float z1[10], z2[10];
        mlp_l1(smem, wb, h1, z1, std::make_index_sequence<10>{});
        mlp_l2(smem, wb, z1, z2, std::make_index_sequence<10>{});
        float o = mlp_dot<W_fW3, 0, 10>(smem, wb, z2, smem[wb + W_fb3],
                                        std::make_index_sequence<10>{});
        out[e * 4 + t] = o;
    }
}

extern "C" void kernel_launch(void* const* d_in, const int* in_sizes, int n_in,
                              void* d_out, int out_size, void* d_ws, size_t ws_size,
                              hipStream_t stream) {
    (void)n_in; (void)d_ws; (void)ws_size;
    const float* y_past   = (const float*)d_in[0];
    const float* x_past   = (const float*)d_in[1];
    const float* u_past   = (const float*)d_in[2];
    const float* s_past   = (const float*)d_in[3];
    const float* u_future = (const float*)d_in[4];
    const float* Wih1_0 = (const float*)d_in[5];
    const float* Whh1_0 = (const float*)d_in[6];
    const float* b1_0   = (const float*)d_in[7];
    const float* Wih1_1 = (const float*)d_in[8];
    const float* Whh1_1 = (const float*)d_in[9];
    const float* b1_1   = (const float*)d_in[10];
    const float* Wih2_0 = (const float*)d_in[11];
    const float* Whh2_0 = (const float*)d_in[12];
    const float* b2_0   = (const float*)d_in[13];
    const float* Wih2_1 = (const float*)d_in[14];
    const float* Whh2_1 = (const float*)d_in[15];
    const float* b2_1   = (const float*)d_in[16];
    const float* fW1 = (const float*)d_in[17];
    const float* fb1 = (const float*)d_in[18];
    const float* fW2 = (const float*)d_in[19];
    const float* fb2 = (const float*)d_in[20];
    const float* fW3 = (const float*)d_in[21];
    const float* fb3 = (const float*)d_in[22];
    float* out = (float*)d_out;

    int B = in_sizes[0] / 8;  // y_past is [B,8,1]
    (void)out_size;

    dim3 block(256);
    dim3 grid((B + 255) / 256);
    lstm_ar_kernel<<<grid, block, 0, stream>>>(
        y_past, x_past, u_past, s_past, u_future,
        Wih1_0, Whh1_0, b1_0, Wih1_1, Whh1_1, b1_1,
        Wih2_0, Whh2_0, b2_0, Wih2_1, Whh2_1, b2_1,
        fW1, fb1, fW2, fb2, fW3, fb3, out, B);
}

// Round 9
// 495.214 us; speedup vs baseline: 1.6616x; 1.2066x over previous
//
#include <hip/hip_runtime.h>
#include <utility>

#define HH 20

typedef float v2f __attribute__((ext_vector_type(2)));

constexpr float LOG2E = 1.4426950408889634f;

// Raw v_rcp_f32 / v_exp_f32 (~1 ulp); harness threshold 1.9e-3.
__device__ __forceinline__ float fast_rcp(float x) { return __builtin_amdgcn_rcpf(x); }
__device__ __forceinline__ float fexp2(float x) {
#if __has_builtin(__builtin_amdgcn_exp2f)
    return __builtin_amdgcn_exp2f(x);
#else
    return exp2f(x);
#endif
}
// sigmoid on a PRE-SCALED argument a' = log2(e)*a: 1/(1+2^-a') = 1/(1+e^-a)
__device__ __forceinline__ float sig2(float x) { return fast_rcp(1.0f + fexp2(-x)); }
// tanh in the unscaled domain (cell state): one mul + exp2.
__device__ __forceinline__ float ftanh(float x) {
    float e = fexp2((2.0f * LOG2E) * x);
    return 1.0f - 2.0f * fast_rcp(e + 1.0f);
}
// DPP quad_perm XOR patterns within each aligned 4-lane quad (VALU pipe).
constexpr int XOR1 = 0xB1;  // [1,0,3,2]
constexpr int XOR2 = 0x4E;  // [2,3,0,1]
constexpr int XOR3 = 0x1B;  // [3,2,1,0]
template <int CTRL>
__device__ __forceinline__ float qdpp(float v) {
    return __int_as_float(__builtin_amdgcn_mov_dpp(__float_as_int(v), CTRL, 0xF, 0xF, true));
}
// v_pk_fma_f32: two independent IEEE fp32 FMAs per instruction.
__device__ __forceinline__ v2f fma2(v2f a, v2f b, v2f c) {
#if __has_builtin(__builtin_elementwise_fma)
    return __builtin_elementwise_fma(a, b, c);
#else
    v2f r; r.x = fmaf(a.x, b.x, c.x); r.y = fmaf(a.y, b.y, c.y); return r;
#endif
}
__device__ __forceinline__ v2f splat2(float w) { return v2f{w, w}; }

// ---- LDS weight arena with per-gate bank pads (R0-verified layout) ----------
// Gate block g at offset g*(20*IN+4): the wave's four concurrent gate-row
// addresses land on disjoint bank quads.
// LSTM weights & biases are PRE-SCALED at staging: gate rows i/f/o by log2e,
// gate g rows by 2*log2e. Activations then use raw v_exp_f32 (2^x) with no
// argument multiplies; the m-trick combine (m*sig - (m-1)) is unchanged.
constexpr int BLK16 = 20 * 16 + 4;   // 324
constexpr int BLK20 = 20 * 20 + 4;   // 404
constexpr int BLK4  = 20 * 4 + 4;    // 84

constexpr int W_Wih1_0 = 0;
constexpr int W_Whh1_0 = W_Wih1_0 + 4 * BLK16;    // 1296
constexpr int W_b1_0   = W_Whh1_0 + 4 * BLK20;    // 2912
constexpr int W_Wih1_1 = W_b1_0 + 80;             // 2992
constexpr int W_Whh1_1 = W_Wih1_1 + 4 * BLK20;    // 4608
constexpr int W_b1_1   = W_Whh1_1 + 4 * BLK20;    // 6224
constexpr int W_Wih2_0 = W_b1_1 + 80;             // 6304
constexpr int W_Whh2_0 = W_Wih2_0 + 4 * BLK4;     // 6640
constexpr int W_b2_0   = W_Whh2_0 + 4 * BLK20;    // 8256
constexpr int W_Wih2_1 = W_b2_0 + 80;             // 8336
constexpr int W_Whh2_1 = W_Wih2_1 + 4 * BLK20;    // 9952
constexpr int W_b2_1   = W_Whh2_1 + 4 * BLK20;    // 11568
constexpr int W_fW1    = W_b2_1 + 80;             // 11648
constexpr int W_fb1    = W_fW1 + 200;             // 11848
constexpr int W_fW2    = W_fb1 + 12;              // 11860
constexpr int W_fb2    = W_fW2 + 100;             // 11960
constexpr int W_fW3    = W_fb2 + 12;              // 11972
constexpr int W_fb3    = W_fW3 + 10;              // 11982
constexpr int LDS_TOT  = W_fb3 + 2;               // 11984 floats = 47.9 KB

// One float4 weight chunk (lane's own gate row) feeds 4 quad elements:
// 8 pk-fma = 16 scalar FMAs per 16B LDS read.
template <int IN, size_t U, size_t K>
__device__ __forceinline__ void rowq_k(const float (&sm)[LDS_TOT], int rb,
                                       const v2f (&p01)[IN], const v2f (&p23)[IN],
                                       v2f& a01, v2f& a23) {
    float4 w = *(const float4*)&sm[rb + (int)(U * IN + 4 * K)];
    v2f w0 = splat2(w.x), w1 = splat2(w.y), w2 = splat2(w.z), w3 = splat2(w.w);
    a01 = fma2(w0, p01[4 * K + 0], a01);  a23 = fma2(w0, p23[4 * K + 0], a23);
    a01 = fma2(w1, p01[4 * K + 1], a01);  a23 = fma2(w1, p23[4 * K + 1], a23);
    a01 = fma2(w2, p01[4 * K + 2], a01);  a23 = fma2(w2, p23[4 * K + 2], a23);
    a01 = fma2(w3, p01[4 * K + 3], a01);  a23 = fma2(w3, p23[4 * K + 3], a23);
}
template <int IN, size_t U, size_t... K>
__device__ __forceinline__ void rowq(const float (&sm)[LDS_TOT], int rb,
                                     const v2f (&p01)[IN], const v2f (&p23)[IN],
                                     v2f& a01, v2f& a23, std::index_sequence<K...>) {
    (rowq_k<IN, U, K>(sm, rb, p01, p23, a01, a23), ...);
}

// One LSTM unit, quad-split: lane q computes gate q (i=0,f=1,g=2,o=3) for the
// quad's 4 elements in LOCAL order (own, q^1, q^2, q^3). Pre-activations come
// out of the dot PRE-SCALED (weights carry log2e / 2*log2e), so activation is
// act = m*sig2(a') - (m-1): sigma for i/f/o lanes (m=1), tanh for g (m=2).
// h[U] is updated IN PLACE (units read only the hp quad copies).
template <int IN, size_t U>
__device__ __forceinline__ void unitq(const float (&sm)[LDS_TOT], bool q0, bool q1,
                                      float m, float mm1, int rih, int rhh, int rb,
                                      const v2f (&xp01)[IN], const v2f (&xp23)[IN],
                                      const v2f (&hp01)[HH], const v2f (&hp23)[HH],
                                      float (&c)[HH], float (&h)[HH]) {
    float bv = sm[rb + (int)U];
    v2f a01 = splat2(bv), a23 = splat2(bv);
    rowq<IN, U>(sm, rih, xp01, xp23, a01, a23, std::make_index_sequence<IN / 4>{});
    rowq<HH, U>(sm, rhh, hp01, hp23, a01, a23, std::make_index_sequence<HH / 4>{});
    float act0 = fmaf(m, sig2(a01.x), -mm1);
    float act1 = fmaf(m, sig2(a01.y), -mm1);
    float act2 = fmaf(m, sig2(a23.x), -mm1);
    float act3 = fmaf(m, sig2(a23.y), -mm1);
    // gather own element's four gates: c_k = gate (q^k) of own element
    float c0 = act0;
    float c1 = qdpp<XOR1>(act1);
    float c2 = qdpp<XOR2>(act2);
    float c3 = qdpp<XOR3>(act3);
    // role un-permute (XOR by q, 2 stages of 4 cndmask) -- verified for q=0..3
    float u0 = q0 ? c1 : c0, u1 = q0 ? c0 : c1, u2 = q0 ? c3 : c2, u3 = q0 ? c2 : c3;
    float si = q1 ? u2 : u0, sf = q1 ? u3 : u1, tg = q1 ? u0 : u2, so = q1 ? u1 : u3;
    float cn = fmaf(sf, c[U], si * tg);
    c[U] = cn;
    h[U] = so * ftanh(cn);
}

// RESTORE: for layer-2 cells the "x" input is the layer-1 h, needed again next
// timestep. Recover it after the units from the quad copy (xp01[K].x) instead
// of keeping it live through the gemm.
template <int WIH, int WHH, int BOFF, int IN, int BLK, bool RESTORE,
          size_t... U, size_t... K>
__device__ __forceinline__ void cell_impl(const float (&sm)[LDS_TOT], int wb, int q,
                                          bool q0, bool q1, float m, float mm1,
                                          float (&x)[IN],
                                          float (&h)[HH], float (&c)[HH],
                                          std::index_sequence<U...>, std::index_sequence<K...>) {
    // quad operand vectors in local order: (own, q^1 | q^2, q^3); 3 DPP/scalar
    v2f xp01[IN], xp23[IN], hp01[HH], hp23[HH];
    ((xp01[K] = v2f{x[K], qdpp<XOR1>(x[K])},
      xp23[K] = v2f{qdpp<XOR2>(x[K]), qdpp<XOR3>(x[K])}), ...);
    ((hp01[U] = v2f{h[U], qdpp<XOR1>(h[U])},
      hp23[U] = v2f{qdpp<XOR2>(h[U]), qdpp<XOR3>(h[U])}), ...);
    const int rih = wb + WIH + q * BLK;    // own gate's row blocks (per-lane addr)
    const int rhh = wb + WHH + q * BLK20;
    const int rb  = wb + BOFF + q * 20;
    (unitq<IN, U>(sm, q0, q1, m, mm1, rih, rhh, rb,
                  xp01, xp23, hp01, hp23, c, h), ...);
    if constexpr (RESTORE) { ((x[K] = xp01[K].x), ...); }
}

template <int WIH, int WHH, int BOFF, int IN, int BLK, bool RESTORE = false>
__device__ __forceinline__ void cell(const float (&sm)[LDS_TOT], int wb, int q,
                                     bool q0, bool q1, float m, float mm1,
                                     float (&x)[IN],
                                     float (&h)[HH], float (&c)[HH]) {
    cell_impl<WIH, WHH, BOFF, IN, BLK, RESTORE>(sm, wb, q, q0, q1, m, mm1, x, h, c,
                                                std::make_index_sequence<HH>{},
                                                std::make_index_sequence<IN>{});
}

// ---- MLP: serial structure (own element, uniform LDS reads, unscaled) ------
template <int WOFF, size_t J, int LD, int NV, size_t... K>
__device__ __forceinline__ float mlp_dot(const float (&sm)[LDS_TOT], int wb, const float (&v)[NV],
                                         float a, std::index_sequence<K...>) {
    ((a = fmaf(sm[wb + WOFF + (int)(J * LD + K)], v[K], a)), ...);
    return a;
}
template <size_t... J>
__device__ __forceinline__ void mlp_l1(const float (&sm)[LDS_TOT], int wb,
                                       const float (&h)[HH], float (&z)[10], std::index_sequence<J...>) {
    ((z[J] = fmaxf(mlp_dot<W_fW1, J, HH>(sm, wb, h, sm[wb + W_fb1 + (int)J],
                                         std::make_index_sequence<HH>{}), 0.f)), ...);
}
template <size_t... J>
__device__ __forceinline__ void mlp_l2(const float (&sm)[LDS_TOT], int wb,
                                       const float (&z1)[10], float (&z2)[10], std::index_sequence<J...>) {
    ((z2[J] = fmaxf(mlp_dot<W_fW2, J, 10>(sm, wb, z1, sm[wb + W_fb2 + (int)J],
                                          std::make_index_sequence<10>{}), 0.f)), ...);
}

// Occupancy truth table (measured R0-R8): VGPR<=128 -> 2 blocks/CU resident;
// VGPR=160 -> 1 block/CU (power-of-2 wave-slot quantum). The 160-VGPR middle
// does not exist. So: lb(256,2) pins the 128 cap + 2 blocks/CU; the R6-proven
// live-set reductions (in-place h, RESTORE) shrink spill excess from ~112 to
// ~32 regs vs R5's 244 MB-spilling 430 us.
__global__ void __launch_bounds__(256, 2) lstm_ar_kernel(
    const float* __restrict__ y_past, const float* __restrict__ x_past,
    const float* __restrict__ u_past, const float* __restrict__ s_past,
    const float* __restrict__ u_future,
    const float* __restrict__ Wih1_0, const float* __restrict__ Whh1_0, const float* __restrict__ b1_0,
    const float* __restrict__ Wih1_1, const float* __restrict__ Whh1_1, const float* __restrict__ b1_1,
    const float* __restrict__ Wih2_0, const float* __restrict__ Whh2_0, const float* __restrict__ b2_0,
    const float* __restrict__ Wih2_1, const float* __restrict__ Whh2_1, const float* __restrict__ b2_1,
    const float* __restrict__ fW1, const float* __restrict__ fb1,
    const float* __restrict__ fW2, const float* __restrict__ fb2,
    const float* __restrict__ fW3, const float* __restrict__ fb3,
    float* __restrict__ out, int B) {
    __shared__ __align__(16) float smem[LDS_TOT];
    const int tid = threadIdx.x;

    // ---- stage weights into LDS with per-gate +4 pads + exp2 pre-scale ----
    // gate 2 (g) rows/biases get 2*log2e, others log2e. MLP stays unscaled.
    auto stage_w = [&](const float* src, int off, int IN) {
        const int gb = 20 * IN;
        for (int i = tid; i < 4 * gb; i += 256) {
            int g = i / gb;
            float s = (g == 2) ? (2.0f * LOG2E) : LOG2E;
            smem[off + g * (gb + 4) + (i - g * gb)] = src[i] * s;
        }
    };
    auto stage_b = [&](const float* src, int off) {
        for (int i = tid; i < 80; i += 256) {
            int g = i / 20;
            float s = (g == 2) ? (2.0f * LOG2E) : LOG2E;
            smem[off + i] = src[i] * s;
        }
    };
    auto stage = [&](const float* src, int off, int n) {
        for (int i = tid; i < n; i += 256) smem[off + i] = src[i];
    };
    stage_w(Wih1_0, W_Wih1_0, 16);
    stage_w(Whh1_0, W_Whh1_0, 20);
    stage_b(b1_0, W_b1_0);
    stage_w(Wih1_1, W_Wih1_1, 20);
    stage_w(Whh1_1, W_Whh1_1, 20);
    stage_b(b1_1, W_b1_1);
    stage_w(Wih2_0, W_Wih2_0, 4);
    stage_w(Whh2_0, W_Whh2_0, 20);
    stage_b(b2_0, W_b2_0);
    stage_w(Wih2_1, W_Wih2_1, 20);
    stage_w(Whh2_1, W_Whh2_1, 20);
    stage_b(b2_1, W_b2_1);
    stage(fW1, W_fW1, 200);
    stage(fb1, W_fb1, 10);
    stage(fW2, W_fW2, 100);
    stage(fb2, W_fb2, 10);
    stage(fW3, W_fW3, 10);
    stage(fb3, W_fb3, 1);
    __syncthreads();

    const int q = tid & 3;                    // quad lane: gate i/f/g/o
    const bool q0 = (tid & 1) != 0;
    const bool q1 = (tid & 2) != 0;
    const int e = blockIdx.x * 256 + tid;     // OWN element == global thread id
    if (e >= B) return;                       // never taken (B % 256 == 0)

    const float m   = (q == 2) ? 2.0f : 1.0f; // tanh for the cell gate
    const float mm1 = m - 1.0f;

    // own-element state only: 80 registers
    float h0[HH], c0[HH], h1[HH], c1[HH];
    {
        auto zero = [&](auto... u) {
            ((h0[u] = 0.f, c0[u] = 0.f, h1[u] = 0.f, c1[u] = 0.f), ...);
        };
        zero(0, 1, 2, 3, 4, 5, 6, 7, 8, 9, 10, 11, 12, 13, 14, 15, 16, 17, 18, 19);
    }

    int wb = 0;  // laundered weight base: re-opaqued per timestep (kills LICM hoist)

    // ---- encoder over lookback T=8 (input = concat[y,x,u,s] = 16 feats) ----
#pragma clang loop unroll(disable)
    for (int t = 0; t < 8; ++t) {
        asm volatile("" : "+s"(wb));
        float x[16];
        x[0] = y_past[e * 8 + t];
        {
            const float4* p = (const float4*)(x_past + (size_t)(e * 8 + t) * 8);
            float4 a0 = p[0], a1 = p[1];
            x[1] = a0.x; x[2] = a0.y; x[3] = a0.z; x[4] = a0.w;
            x[5] = a1.x; x[6] = a1.y; x[7] = a1.z; x[8] = a1.w;
        }
        {
            const float4* p = (const float4*)(u_past + (size_t)(e * 8 + t) * 4);
            float4 a0 = p[0];
            x[9] = a0.x; x[10] = a0.y; x[11] = a0.z; x[12] = a0.w;
        }
        {
            const float* p = s_past + (size_t)(e * 8 + t) * 3;
            x[13] = p[0]; x[14] = p[1]; x[15] = p[2];
        }
        cell<W_Wih1_0, W_Whh1_0, W_b1_0, 16, BLK16>(smem, wb, q, q0, q1, m, mm1, x, h0, c0);
        cell<W_Wih1_1, W_Whh1_1, W_b1_1, HH, BLK20, true>(smem, wb, q, q0, q1, m, mm1, h0, h1, c1);
    }

    // ---- decoder over lookahead T=4 (input = u_future, 4 feats) + MLP head ----
#pragma clang loop unroll(disable)
    for (int t = 0; t < 4; ++t) {
        asm volatile("" : "+s"(wb));
        float x[4];
        {
            const float4* p = (const float4*)(u_future + (size_t)(e * 4 + t) * 4);
            float4 a0 = p[0];
            x[0] = a0.x; x[1] = a0.y; x[2] = a0.z; x[3] = a0.w;
        }
        cell<W_Wih2_0, W_Whh2_0, W_b2_0, 4, BLK4>(smem, wb, q, q0, q1, m, mm1, x, h0, c0);
        cell<W_Wih2_1, W_Whh2_1, W_b2_1, HH, BLK20, true>(smem, wb, q, q0, q1, m, mm1, h0, h1, c1);

        // FCNN 20 -> 10 -> 10 -> 1 on OWN element's h1
        float z1[10], z2[10];
        mlp_l1(smem, wb, h1, z1, std::make_index_sequence<10>{});
        mlp_l2(smem, wb, z1, z2, std::make_index_sequence<10>{});
        float o = mlp_dot<W_fW3, 0, 10>(smem, wb, z2, smem[wb + W_fb3],
                                        std::make_index_sequence<10>{});
        out[e * 4 + t] = o;
    }
}

extern "C" void kernel_launch(void* const* d_in, const int* in_sizes, int n_in,
                              void* d_out, int out_size, void* d_ws, size_t ws_size,
                              hipStream_t stream) {
    (void)n_in; (void)d_ws; (void)ws_size;
    const float* y_past   = (const float*)d_in[0];
    const float* x_past   = (const float*)d_in[1];
    const float* u_past   = (const float*)d_in[2];
    const float* s_past   = (const float*)d_in[3];
    const float* u_future = (const float*)d_in[4];
    const float* Wih1_0 = (const float*)d_in[5];
    const float* Whh1_0 = (const float*)d_in[6];
    const float* b1_0   = (const float*)d_in[7];
    const float* Wih1_1 = (const float*)d_in[8];
    const float* Whh1_1 = (const float*)d_in[9];
    const float* b1_1   = (const float*)d_in[10];
    const float* Wih2_0 = (const float*)d_in[11];
    const float* Whh2_0 = (const float*)d_in[12];
    const float* b2_0   = (const float*)d_in[13];
    const float* Wih2_1 = (const float*)d_in[14];
    const float* Whh2_1 = (const float*)d_in[15];
    const float* b2_1   = (const float*)d_in[16];
    const float* fW1 = (const float*)d_in[17];
    const float* fb1 = (const float*)d_in[18];
    const float* fW2 = (const float*)d_in[19];
    const float* fb2 = (const float*)d_in[20];
    const float* fW3 = (const float*)d_in[21];
    const float* fb3 = (const float*)d_in[22];
    float* out = (float*)d_out;

    int B = in_sizes[0] / 8;  // y_past is [B,8,1]
    (void)out_size;

    dim3 block(256);
    dim3 grid((B + 255) / 256);
    lstm_ar_kernel<<<grid, block, 0, stream>>>(
        y_past, x_past, u_past, s_past, u_future,
        Wih1_0, Whh1_0, b1_0, Wih1_1, Whh1_1, b1_1,
        Wih2_0, Whh2_0, b2_0, Wih2_1, Whh2_1, b2_1,
        fW1, fb1, fW2, fb2, fW3, fb3, out, B);
}